// Round 1
// baseline (170.129 us; speedup 1.0000x reference)
//
#include <hip/hip_runtime.h>

#define NBATCH 16
#define NTGT   50
#define NA     3
#define NH     76
#define NW     76
#define HW     (NH*NW)        // 5776
#define NC     80
#define NATT   85
#define CELLS  (NA*HW)        // 17328 per batch

__device__ __constant__ float c_anchors[18] = {
  10.f,13.f, 16.f,30.f, 33.f,23.f, 30.f,61.f, 62.f,45.f,
  59.f,119.f, 116.f,90.f, 156.f,198.f, 373.f,326.f };

// workspace layout in 4-byte words (total 8816 words = ~35 KB)
#define OFF_GX   0
#define OFF_GY   800
#define OFF_GW   1600
#define OFF_GH   2400
#define OFF_TX   3200
#define OFF_TY   4000
#define OFF_TW   4800
#define OFF_TH   5600
#define OFF_CV   6400
#define OFF_WKEY 7200
#define OFF_CLS  8000
#define OFF_NV   8800

// img_dim arrives as a 1-element array; dtype (int32 vs fp32) is ambiguous.
// 608 as int32 = 0x260 (tiny); 608.0f bit-pattern = 0x44180000 (huge as int).
__device__ inline float read_dim(const void* p) {
  int iv = *(const int*)p;
  if (iv > 0 && iv < (1 << 24)) return (float)iv;
  return *(const float*)p;
}

__global__ void yolo_prep(const float* __restrict__ tgt,
                          const void*  __restrict__ dimp,
                          float*       __restrict__ wsf) {
  int tid = threadIdx.x;
  int* wsi = (int*)wsf;
  if (tid < NBATCH) wsi[OFF_NV + tid] = NTGT;
  __syncthreads();
  if (tid < NBATCH * NTGT) {
    float stride = read_dim(dimp) / (float)NH;          // 608/76 = 8 exactly
    float inv_stride = 1.0f / stride;
    int b = tid / NTGT;
    const float* tr = tgt + tid * 5;
    float cls = tr[0], cx = tr[1], cy = tr[2], w = tr[3], h = tr[4];
    float s = cls + cx + cy + w + h;
    if (s == 0.0f) atomicMin(&wsi[OFF_NV + b], tid - b * NTGT);  // valid = cumprod prefix
    float gx = cx * NW, gy = cy * NH, gw = w * NW, gh = h * NH;
    int gi = min(max((int)gx, 0), NW - 1);
    int gj = min(max((int)gy, 0), NH - 1);
    // best anchor over all 9 (wh-only IoU), first-max wins (strict >)
    float best_r = -1.0f; int best = 0;
    for (int k = 0; k < 9; k++) {
      float aw = c_anchors[2*k] * inv_stride, ah = c_anchors[2*k+1] * inv_stride;
      float inter = fminf(gw, aw) * fminf(gh, ah);
      float uni   = gw * gh + aw * ah - inter;
      float r = inter / (uni + 1e-16f);
      if (r > best_r) { best_r = r; best = k; }
    }
    int a_loc = (best < NA) ? best : 0;                 // clipped, only used if write
    int wkey  = (best < NA) ? (a_loc * HW + gj * NW + gi) : -1;
    float aw = c_anchors[2*a_loc] * inv_stride, ah = c_anchors[2*a_loc+1] * inv_stride;
    wsf[OFF_GX + tid] = gx;  wsf[OFF_GY + tid] = gy;
    wsf[OFF_GW + tid] = gw;  wsf[OFF_GH + tid] = gh;
    wsf[OFF_TX + tid] = gx - (float)gi;
    wsf[OFF_TY + tid] = gy - (float)gj;
    wsf[OFF_TW + tid] = logf(gw / aw + 1e-16f);
    wsf[OFF_TH + tid] = logf(gh / ah + 1e-16f);
    wsf[OFF_CV + tid] = sqrtf(2.0f - w * h);
    int ci = (int)cls; ci = min(max(ci, 0), NC - 1);
    wsi[OFF_WKEY + tid] = wkey;
    wsi[OFF_CLS  + tid] = ci;
  }
}

__launch_bounds__(256)
__global__ void yolo_main(const float* __restrict__ x,
                          const float* __restrict__ wsf,
                          const void*  __restrict__ dimp,
                          float*       __restrict__ out) {
  __shared__ float sx1[NTGT], sx2[NTGT], sy1[NTGT], sy2[NTGT], sarea[NTGT];
  __shared__ float stx[NTGT], sty[NTGT], stw[NTGT], sth[NTGT], scv[NTGT];
  __shared__ int   swkey[NTGT], scls[NTGT];
  __shared__ int   snv;
  __shared__ float sred[4];

  int b   = blockIdx.y;
  int tid = threadIdx.x;
  if (tid < NTGT) {
    int g = b * NTGT + tid;
    float gx = wsf[OFF_GX+g], gy = wsf[OFF_GY+g], gw = wsf[OFF_GW+g], gh = wsf[OFF_GH+g];
    sx1[tid] = gx - gw * 0.5f;  sx2[tid] = gx + gw * 0.5f;
    sy1[tid] = gy - gh * 0.5f;  sy2[tid] = gy + gh * 0.5f;
    sarea[tid] = gw * gh;
    stx[tid] = wsf[OFF_TX+g];  sty[tid] = wsf[OFF_TY+g];
    stw[tid] = wsf[OFF_TW+g];  sth[tid] = wsf[OFF_TH+g];
    scv[tid] = wsf[OFF_CV+g];
    const int* wsi = (const int*)wsf;
    swkey[tid] = wsi[OFF_WKEY+g];
    scls[tid]  = wsi[OFF_CLS +g];
  }
  if (tid == 0) snv = ((const int*)wsf)[OFF_NV + b];
  __syncthreads();

  float loss = 0.0f;
  int cell = blockIdx.x * blockDim.x + tid;        // a*HW + j*NW + i within batch
  if (cell < CELLS) {
    int a   = cell / HW;
    int rem = cell - a * HW;                       // j*NW + i (contiguous in x)
    int j   = rem / NW;
    int i   = rem - j * NW;
    const float* xb = x + (size_t)(b * (NA*NATT) + a * NATT) * HW + rem;
    float px = xb[0*HW], py = xb[1*HW], pw = xb[2*HW], ph = xb[3*HW], pc = xb[4*HW];
    float spx   = 1.0f / (1.0f + __expf(-px));
    float spy   = 1.0f / (1.0f + __expf(-py));
    float sconf = 1.0f / (1.0f + __expf(-pc));
    float stride = read_dim(dimp) / (float)NH;
    float aw = c_anchors[2*a] / stride, ah = c_anchors[2*a+1] / stride;
    float bw = __expf(pw) * aw, bh = __expf(ph) * ah;
    float bx = spx + (float)i, by = spy + (float)j;
    float ax1 = bx - bw * 0.5f, ax2 = bx + bw * 0.5f;
    float ay1 = by - bh * 0.5f, ay2 = by + bh * 0.5f;
    float areaA = bw * bh;

    int winner = -1;
    unsigned cb0 = 0, cb1 = 0, cb2 = 0;            // 80-bit class set at this cell
    bool ign = false;
    int nv = snv;
    for (int t = 0; t < nv; t++) {                 // ascending t => last-write-wins
      float iw = fmaxf(fminf(ax2, sx2[t]) - fmaxf(ax1, sx1[t]), 0.0f);
      float ih = fmaxf(fminf(ay2, sy2[t]) - fmaxf(ay1, sy1[t]), 0.0f);
      float inter = iw * ih;
      float iou = inter / (areaA + sarea[t] - inter + 1e-16f);
      ign = ign | (iou > 0.7f);
      if (swkey[t] == cell) {
        winner = t;
        int c = scls[t];
        if (c < 32)      cb0 |= (1u << c);
        else if (c < 64) cb1 |= (1u << (c - 32));
        else             cb2 |= (1u << (c - 64));
      }
    }
    // conf loss, noobj part: -log(1 - conf*noobj + EPS); zero (in fp32) when ignored
    if (!ign) loss += -__logf(1.0f - sconf + 1e-12f);
    if (winner >= 0) {
      // conf loss, obj part
      loss += -__logf(sconf + 1e-12f);
      // coord losses
      float m  = scv[winner];
      float dx = (spx - stx[winner]) * m;
      float dy = (spy - sty[winner]) * m;
      float dw = (pw  - stw[winner]) * m;
      float dh = (ph  - sth[winner]) * m;
      loss += 0.5f * (dx*dx + dy*dy + dw*dw + dh*dh);
      // class BCE — only obj cells touch the 80 class channels
      for (int c = 0; c < NC; c++) {
        float pv = 1.0f / (1.0f + __expf(-xb[(5 + c) * HW]));
        bool on = (c < 32) ? ((cb0 >> c) & 1u)
                : (c < 64) ? ((cb1 >> (c - 32)) & 1u)
                           : ((cb2 >> (c - 64)) & 1u);
        loss += on ? -__logf(pv + 1e-12f) : -__logf(1.0f - pv + 1e-12f);
      }
    }
  }

  // wave-64 shuffle reduce, then cross-wave via LDS, one atomic per block
  for (int off = 32; off > 0; off >>= 1) loss += __shfl_down(loss, off, 64);
  int wave = tid >> 6, lane = tid & 63;
  if (lane == 0) sred[wave] = loss;
  __syncthreads();
  if (tid == 0) {
    atomicAdd(out, sred[0] + sred[1] + sred[2] + sred[3]);
  }
}

extern "C" void kernel_launch(void* const* d_in, const int* in_sizes, int n_in,
                              void* d_out, int out_size, void* d_ws, size_t ws_size,
                              hipStream_t stream) {
  const float* x    = (const float*)d_in[0];
  const float* tgt  = (const float*)d_in[1];
  const void*  dimp = d_in[2];
  float* out = (float*)d_out;
  float* wsf = (float*)d_ws;

  // harness poisons d_out with 0xAA — zero it (we accumulate via atomicAdd)
  hipMemsetAsync(out, 0, sizeof(float) * out_size, stream);

  yolo_prep<<<1, 832, 0, stream>>>(tgt, dimp, wsf);

  dim3 grid((CELLS + 255) / 256, NBATCH);
  yolo_main<<<grid, 256, 0, stream>>>(x, wsf, dimp, out);
}

// Round 2
// 167.738 us; speedup vs baseline: 1.0143x; 1.0143x over previous
//
#include <hip/hip_runtime.h>

#define NBATCH 16
#define NTGT   50
#define NA     3
#define NH     76
#define NW     76
#define HW     (NH*NW)        // 5776
#define NC     80
#define NATT   85
#define CELLS  (NA*HW)        // 17328 per batch

__device__ __constant__ float c_anchors[18] = {
  10.f,13.f, 16.f,30.f, 33.f,23.f, 30.f,61.f, 62.f,45.f,
  59.f,119.f, 116.f,90.f, 156.f,198.f, 373.f,326.f };

// ws layout (words): [0..3199] float4 box[16][50] {x1,x2,y1,y2}
//                    [3200..3999] float area[16][50]
//                    [4000..4015] int nv[16]
#define OFF_AREA 3200
#define OFF_NV   4000

// img_dim arrives as a 1-element array; dtype (int32 vs fp32) ambiguous.
// 608 as int32 = 0x260 (tiny); 608.0f = 0x44180000 (huge as int).
__device__ inline float read_dim(const void* p) {
  int iv = *(const int*)p;
  if (iv > 0 && iv < (1 << 24)) return (float)iv;
  return *(const float*)p;
}

// One block per batch, one wave (64 threads). Lanes 0..49 own targets.
// Computes: per-target IoU boxes -> ws; per-batch nvalid -> ws;
// and the FULL obj-cell loss (conf-obj + coord + 80-class BCE) for winner
// targets (last-write-wins per cell key), atomicAdd'ed into out.
__global__ void yolo_prep_obj(const float* __restrict__ tgt,
                              const float* __restrict__ x,
                              const void*  __restrict__ dimp,
                              float*       __restrict__ wsf,
                              float*       __restrict__ out) {
  __shared__ int skey[NTGT];
  __shared__ int scl [NTGT];
  int b = blockIdx.x;
  int t = threadIdx.x;
  float istride = (float)NH / read_dim(dimp);   // 1/stride = 76/608

  float cls = 0.f, cx = 0.f, cy = 0.f, w = 0.f, h = 0.f, s = 1.f;
  if (t < NTGT) {
    const float* tr = tgt + (size_t)(b * NTGT + t) * 5;
    cls = tr[0]; cx = tr[1]; cy = tr[2]; w = tr[3]; h = tr[4];
    s = cls + cx + cy + w + h;
  }
  // valid = cumprod(sum != 0) prefix -> first all-zero row truncates
  unsigned long long mz = __ballot(t < NTGT && s == 0.0f);
  int nv = mz ? (__ffsll(mz) - 1) : NTGT;

  float gx = cx * NW, gy = cy * NH, gw = w * NW, gh = h * NH;
  int gi = min(max((int)gx, 0), NW - 1);
  int gj = min(max((int)gy, 0), NH - 1);

  // best of 9 anchors (wh-only IoU), first-max wins (strict >)
  float best_r = -1.0f; int best = 0;
  for (int k = 0; k < 9; k++) {
    float aw = c_anchors[2*k] * istride, ah = c_anchors[2*k+1] * istride;
    float inter = fminf(gw, aw) * fminf(gh, ah);
    float uni   = gw * gh + aw * ah - inter;
    float r = inter / (uni + 1e-16f);
    if (r > best_r) { best_r = r; best = k; }
  }
  int a = (best < NA) ? best : 0;
  int mykey = (t < nv && best < NA) ? (a * HW + gj * NW + gi) : -1;

  if (t < NTGT) {
    skey[t] = mykey;
    scl [t] = min(max((int)cls, 0), NC - 1);
    // stage IoU box for the main kernel
    float4* wbox = (float4*)wsf;
    wbox[b * NTGT + t] = make_float4(gx - gw*0.5f, gx + gw*0.5f,
                                     gy - gh*0.5f, gy + gh*0.5f);
    wsf[OFF_AREA + b * NTGT + t] = gw * gh;
  }
  if (t == 0) ((int*)wsf)[OFF_NV + b] = nv;
  __syncthreads();

  float loss = 0.0f;
  if (mykey >= 0) {
    // winner iff no later valid target writes the same cell; classes = union
    bool winner = true;
    unsigned cb0 = 0, cb1 = 0, cb2 = 0;
    for (int t2 = 0; t2 < nv; t2++) {
      if (skey[t2] == mykey) {
        if (t2 > t) winner = false;
        int c = scl[t2];
        if (c < 32)      cb0 |= (1u << c);
        else if (c < 64) cb1 |= (1u << (c - 32));
        else             cb2 |= (1u << (c - 64));
      }
    }
    if (winner) {
      const float* xb = x + ((size_t)(b * NA + a) * NATT) * HW + gj * NW + gi;
      float px = xb[0*HW], py = xb[1*HW], pw = xb[2*HW], ph = xb[3*HW], pc = xb[4*HW];
      float spx   = 1.0f / (1.0f + __expf(-px));
      float spy   = 1.0f / (1.0f + __expf(-py));
      float sconf = 1.0f / (1.0f + __expf(-pc));
      float aw = c_anchors[2*a] * istride, ah = c_anchors[2*a+1] * istride;
      // conf obj term
      loss += -__logf(sconf + 1e-12f);
      // coord terms
      float m  = sqrtf(2.0f - w * h);
      float dx = (spx - (gx - (float)gi)) * m;
      float dy = (spy - (gy - (float)gj)) * m;
      float dw = (pw  - __logf(gw / aw + 1e-16f)) * m;
      float dh = (ph  - __logf(gh / ah + 1e-16f)) * m;
      loss += 0.5f * (dx*dx + dy*dy + dw*dw + dh*dh);
      // class BCE over 80 channels
      for (int c = 0; c < NC; c++) {
        float pv = 1.0f / (1.0f + __expf(-xb[(5 + c) * HW]));
        bool on = (c < 32) ? ((cb0 >> c) & 1u)
                : (c < 64) ? ((cb1 >> (c - 32)) & 1u)
                           : ((cb2 >> (c - 64)) & 1u);
        loss += on ? -__logf(pv + 1e-12f) : -__logf(1.0f - pv + 1e-12f);
      }
    }
  }
  for (int off = 32; off > 0; off >>= 1) loss += __shfl_down(loss, off, 64);
  if (t == 0) atomicAdd(out, loss);
}

// One thread per (a,j,i) cell; blockIdx.y = batch. Lean loop: pred box,
// 50-target division-free ignore test, noobj conf loss. No winner logic.
__launch_bounds__(256)
__global__ void yolo_noobj(const float* __restrict__ x,
                           const float* __restrict__ wsf,
                           const void*  __restrict__ dimp,
                           float*       __restrict__ out) {
  __shared__ float4 sbox[NTGT];
  __shared__ float  sarea[NTGT];
  __shared__ int    snv;
  __shared__ float  sred[4];

  int b   = blockIdx.y;
  int tid = threadIdx.x;
  if (tid < NTGT) {
    sbox [tid] = ((const float4*)wsf)[b * NTGT + tid];
    sarea[tid] = wsf[OFF_AREA + b * NTGT + tid];
  }
  if (tid == 0) snv = ((const int*)wsf)[OFF_NV + b];
  __syncthreads();

  float loss = 0.0f;
  int cell = blockIdx.x * blockDim.x + tid;     // a*HW + j*NW + i
  if (cell < CELLS) {
    int a   = cell / HW;
    int rem = cell - a * HW;
    int j   = rem / NW;
    int i   = rem - j * NW;
    const float* xb = x + ((size_t)(b * NA + a) * NATT) * HW + rem;
    float px = xb[0*HW], py = xb[1*HW], pw = xb[2*HW], ph = xb[3*HW], pc = xb[4*HW];
    float spx   = 1.0f / (1.0f + __expf(-px));
    float spy   = 1.0f / (1.0f + __expf(-py));
    float sconf = 1.0f / (1.0f + __expf(-pc));
    float istride = (float)NH / read_dim(dimp);
    float bw = __expf(pw) * c_anchors[2*a]   * istride;
    float bh = __expf(ph) * c_anchors[2*a+1] * istride;
    float bx = spx + (float)i, by = spy + (float)j;
    float ax1 = bx - bw * 0.5f, ax2 = bx + bw * 0.5f;
    float ay1 = by - bh * 0.5f, ay2 = by + bh * 0.5f;
    float areaA = bw * bh;

    bool ign = false;
    int nv = snv;
    for (int t = 0; t < nv; t++) {
      float4 bb = sbox[t];                       // {x1,x2,y1,y2} broadcast
      float iw = fmaxf(fminf(ax2, bb.y) - fmaxf(ax1, bb.x), 0.0f);
      float ih = fmaxf(fminf(ay2, bb.w) - fmaxf(ay1, bb.z), 0.0f);
      float inter = iw * ih;
      float uni   = areaA + sarea[t] - inter + 1e-16f;
      ign = ign | (inter > 0.7f * uni);          // iou > 0.7, division-free
    }
    if (!ign) loss += -__logf(1.0f - sconf + 1e-12f);
  }

  for (int off = 32; off > 0; off >>= 1) loss += __shfl_down(loss, off, 64);
  int wave = tid >> 6, lane = tid & 63;
  if (lane == 0) sred[wave] = loss;
  __syncthreads();
  if (tid == 0) atomicAdd(out, sred[0] + sred[1] + sred[2] + sred[3]);
}

extern "C" void kernel_launch(void* const* d_in, const int* in_sizes, int n_in,
                              void* d_out, int out_size, void* d_ws, size_t ws_size,
                              hipStream_t stream) {
  const float* x    = (const float*)d_in[0];
  const float* tgt  = (const float*)d_in[1];
  const void*  dimp = d_in[2];
  float* out = (float*)d_out;
  float* wsf = (float*)d_ws;

  // d_out is poisoned 0xAA — zero before accumulating
  hipMemsetAsync(out, 0, sizeof(float) * out_size, stream);

  yolo_prep_obj<<<NBATCH, 64, 0, stream>>>(tgt, x, dimp, wsf, out);

  dim3 grid((CELLS + 255) / 256, NBATCH);
  yolo_noobj<<<grid, 256, 0, stream>>>(x, wsf, dimp, out);
}

// Round 3
// 150.862 us; speedup vs baseline: 1.1277x; 1.1119x over previous
//
#include <hip/hip_runtime.h>

#define NBATCH 16
#define NTGT   50
#define NA     3
#define NH     76
#define NW     76
#define HW     (NH*NW)        // 5776
#define NC     80
#define NATT   85
#define CELLS  (NA*HW)        // 17328 per batch
#define CBLK   68             // cell blocks per batch (68*256 = 17408 >= CELLS)
#define BPB    (CBLK + 1)     // +1 obj block per batch
#define NPART  (BPB * NBATCH) // 1104 partial sums

__device__ __constant__ float c_anchors[18] = {
  10.f,13.f, 16.f,30.f, 33.f,23.f, 30.f,61.f, 62.f,45.f,
  59.f,119.f, 116.f,90.f, 156.f,198.f, 373.f,326.f };

// img_dim arrives as a 1-element array; dtype (int32 vs fp32) ambiguous.
// 608 as int32 = 0x260 (tiny); 608.0f = 0x44180000 (huge as int).
__device__ inline float read_dim(const void* p) {
  int iv = *(const int*)p;
  if (iv > 0 && iv < (1 << 24)) return (float)iv;
  return *(const float*)p;
}

// Fused kernel. blockIdx.y = batch. blockIdx.x in [0,67]: noobj cells.
// blockIdx.x == 68: obj-cell loss (winner targets) on wave 0.
// Every block recomputes the 50-target prep (trivial) — no staging kernel.
// Each block writes ONE partial sum to wsf[b*BPB + bx]; no atomics, no memset.
__launch_bounds__(256)
__global__ void yolo_all(const float* __restrict__ x,
                         const float* __restrict__ tgt,
                         const void*  __restrict__ dimp,
                         float*       __restrict__ wsf) {
  __shared__ float4 sbox[NTGT];
  __shared__ float  sarea[NTGT];
  __shared__ int    skey[NTGT];
  __shared__ int    scl [NTGT];
  __shared__ int    snv;
  __shared__ float  sred[4];

  int b   = blockIdx.y;
  int bx  = blockIdx.x;
  int tid = threadIdx.x;
  float istride = (float)NH / read_dim(dimp);   // 1/stride = 76/608

  // ---- per-target prep (wave 0 only; lanes 0..49 own targets) ----
  float gx = 0.f, gy = 0.f, gw = 0.f, gh = 0.f, w = 0.f, h = 0.f;
  int   gi = 0, gj = 0, a = 0, mykey = -1;
  if (tid < 64) {
    float cls = 0.f, cx = 0.f, cy = 0.f, s = 1.f;
    if (tid < NTGT) {
      const float* tr = tgt + (size_t)(b * NTGT + tid) * 5;
      cls = tr[0]; cx = tr[1]; cy = tr[2]; w = tr[3]; h = tr[4];
      s = cls + cx + cy + w + h;
    }
    // valid = cumprod(sum != 0) prefix -> first all-zero row truncates
    unsigned long long mz = __ballot(tid < NTGT && s == 0.0f);
    int nv = mz ? (__ffsll(mz) - 1) : NTGT;

    gx = cx * NW; gy = cy * NH; gw = w * NW; gh = h * NH;
    gi = min(max((int)gx, 0), NW - 1);
    gj = min(max((int)gy, 0), NH - 1);

    // best of 9 anchors (wh-only IoU), first-max wins (strict >)
    float best_r = -1.0f; int best = 0;
    for (int k = 0; k < 9; k++) {
      float aw = c_anchors[2*k] * istride, ah = c_anchors[2*k+1] * istride;
      float inter = fminf(gw, aw) * fminf(gh, ah);
      float uni   = gw * gh + aw * ah - inter;
      float r = inter / (uni + 1e-16f);
      if (r > best_r) { best_r = r; best = k; }
    }
    a = (best < NA) ? best : 0;
    mykey = (tid < nv && best < NA) ? (a * HW + gj * NW + gi) : -1;

    if (tid < NTGT) {
      sbox[tid]  = make_float4(gx - gw*0.5f, gx + gw*0.5f,
                               gy - gh*0.5f, gy + gh*0.5f);
      sarea[tid] = gw * gh;
      skey[tid]  = mykey;
      scl [tid]  = min(max((int)cls, 0), NC - 1);
    }
    if (tid == 0) snv = nv;
  }
  __syncthreads();

  float loss = 0.0f;
  int nv = snv;

  if (bx < CBLK) {
    // ---- noobj path: one thread per (a,j,i) cell ----
    int cell = bx * 256 + tid;
    if (cell < CELLS) {
      int ca  = cell / HW;
      int rem = cell - ca * HW;
      int j   = rem / NW;
      int i   = rem - j * NW;
      const float* xb = x + ((size_t)(b * NA + ca) * NATT) * HW + rem;
      float px = xb[0*HW], py = xb[1*HW], pw = xb[2*HW], ph = xb[3*HW], pc = xb[4*HW];
      float spx   = 1.0f / (1.0f + __expf(-px));
      float spy   = 1.0f / (1.0f + __expf(-py));
      float sconf = 1.0f / (1.0f + __expf(-pc));
      float bw = __expf(pw) * c_anchors[2*ca]   * istride;
      float bh = __expf(ph) * c_anchors[2*ca+1] * istride;
      float bxc = spx + (float)i, byc = spy + (float)j;
      float ax1 = bxc - bw * 0.5f, ax2 = bxc + bw * 0.5f;
      float ay1 = byc - bh * 0.5f, ay2 = byc + bh * 0.5f;
      float areaA = bw * bh;

      bool ign = false;
      for (int t = 0; t < nv; t++) {
        float4 bb = sbox[t];                     // {x1,x2,y1,y2} broadcast
        float iw = fmaxf(fminf(ax2, bb.y) - fmaxf(ax1, bb.x), 0.0f);
        float ih = fmaxf(fminf(ay2, bb.w) - fmaxf(ay1, bb.z), 0.0f);
        float inter = iw * ih;
        float uni   = areaA + sarea[t] - inter + 1e-16f;
        ign = ign | (inter > 0.7f * uni);        // iou > 0.7, division-free
      }
      if (!ign) loss = -__logf(1.0f - sconf + 1e-12f);
    }
  } else if (tid < 64 && mykey >= 0) {
    // ---- obj path: winner iff no later valid target has same key ----
    bool winner = true;
    unsigned cb0 = 0, cb1 = 0, cb2 = 0;          // class union at this cell
    for (int t2 = 0; t2 < nv; t2++) {
      if (skey[t2] == mykey) {
        if (t2 > tid) winner = false;
        int c = scl[t2];
        if (c < 32)      cb0 |= (1u << c);
        else if (c < 64) cb1 |= (1u << (c - 32));
        else             cb2 |= (1u << (c - 64));
      }
    }
    if (winner) {
      const float* xb = x + ((size_t)(b * NA + a) * NATT) * HW + gj * NW + gi;
      float px = xb[0*HW], py = xb[1*HW], pw = xb[2*HW], ph = xb[3*HW], pc = xb[4*HW];
      float spx   = 1.0f / (1.0f + __expf(-px));
      float spy   = 1.0f / (1.0f + __expf(-py));
      float sconf = 1.0f / (1.0f + __expf(-pc));
      float aw = c_anchors[2*a] * istride, ah = c_anchors[2*a+1] * istride;
      loss += -__logf(sconf + 1e-12f);           // conf obj term
      float m  = sqrtf(2.0f - w * h);
      float dx = (spx - (gx - (float)gi)) * m;
      float dy = (spy - (gy - (float)gj)) * m;
      float dw = (pw  - __logf(gw / aw + 1e-16f)) * m;
      float dh = (ph  - __logf(gh / ah + 1e-16f)) * m;
      loss += 0.5f * (dx*dx + dy*dy + dw*dw + dh*dh);
      for (int c = 0; c < NC; c++) {             // class BCE, 80 channels
        float pv = 1.0f / (1.0f + __expf(-xb[(5 + c) * HW]));
        bool on = (c < 32) ? ((cb0 >> c) & 1u)
                : (c < 64) ? ((cb1 >> (c - 32)) & 1u)
                           : ((cb2 >> (c - 64)) & 1u);
        loss += on ? -__logf(pv + 1e-12f) : -__logf(1.0f - pv + 1e-12f);
      }
    }
  }

  // block reduce -> one partial per block (deterministic, no atomics)
  for (int off = 32; off > 0; off >>= 1) loss += __shfl_down(loss, off, 64);
  int wave = tid >> 6, lane = tid & 63;
  if (lane == 0) sred[wave] = loss;
  __syncthreads();
  if (tid == 0) wsf[b * BPB + bx] = sred[0] + sred[1] + sred[2] + sred[3];
}

// Sum the 1104 partials -> d_out[0] (direct store, no memset needed).
__global__ void yolo_reduce(const float* __restrict__ wsf,
                            float*       __restrict__ out) {
  __shared__ float sred[4];
  int tid = threadIdx.x;                          // 256 threads
  float s = 0.0f;
  for (int i = tid; i < NPART; i += 256) s += wsf[i];
  for (int off = 32; off > 0; off >>= 1) s += __shfl_down(s, off, 64);
  int wave = tid >> 6, lane = tid & 63;
  if (lane == 0) sred[wave] = s;
  __syncthreads();
  if (tid == 0) out[0] = sred[0] + sred[1] + sred[2] + sred[3];
}

extern "C" void kernel_launch(void* const* d_in, const int* in_sizes, int n_in,
                              void* d_out, int out_size, void* d_ws, size_t ws_size,
                              hipStream_t stream) {
  const float* x    = (const float*)d_in[0];
  const float* tgt  = (const float*)d_in[1];
  const void*  dimp = d_in[2];
  float* out = (float*)d_out;
  float* wsf = (float*)d_ws;

  dim3 grid(BPB, NBATCH);
  yolo_all<<<grid, 256, 0, stream>>>(x, tgt, dimp, wsf);
  yolo_reduce<<<1, 256, 0, stream>>>(wsf, out);
}